// Round 7
// baseline (13.876 us; speedup 1.0000x reference)
//
#include <hip/hip_runtime.h>

// ---------------------------------------------------------------------------
// Fused RK4-ish integrator cell with RBF drift term. Output depends only on
// u and y1 = states[1]:
//   d1  = (u - KK*y1 - OFFST - r(y1)) * M          (KK = F_V + F_C)
//   lin = 6*y1 + 3*DT*d1
//   st0 = -(DT/6)*M * lin
//   st1 =  (DT/6)*M * (6u - KK*lin - 6*OFFST - rsum)
// rsum = r(y1) + 4 r(y1+.5*DT*d1) + r(y1+DT*d1) ~= 6*r0 + (sl/h)*3*DT*d1
// (first-order Taylor; verified absmax 2.4e-4 vs threshold 1.23e-3).
//
// R6 lessons: NT stores regressed (working set is L2-resident across replays;
// forcing writes to HBM costs ~1us) -> plain stores. This round:
//   - 16 elems/thread, 256 blocks (1 block/CU): halves the redundant
//     table-build wall time (1 build-wave/SIMD instead of 2).
//   - SoA LUT (val[]/slope[] as two ds_read_b32) instead of float2 AoS:
//     random-index 2-way conflicts (free) vs 4-8-way on ds_read_b64.
//   - all 8 input v4f loads issued before the table build (ILP covers the
//     1-wave/SIMD main phase).
// ---------------------------------------------------------------------------

typedef float v4f __attribute__((ext_vector_type(4)));

#define NTAB   256
#define XMIN   (-8.0f)
#define HSTEP  0.0625f       // 16/256, exact pow2
#define INVH   16.0f
#define TOFF   128.0f        // -XMIN*INVH
#define SMAX   254.999f      // clamp so i+1 <= 255 (slope[255] unused)
#define EPT    16            // elements per thread

__device__ __constant__ const float kM     = (float)(1.0 / 95.45);
__device__ __constant__ const float kOFFST = -3.2902f;
__device__ __constant__ const float kKK    = 214.9261f + 19.3607f;  // F_V+F_C
__device__ __constant__ const float kC1    = (0.005f / 6.0f) * (float)(1.0 / 95.45);

__device__ __forceinline__ void rk_core(const float* __restrict__ lval,
                                        const float* __restrict__ lslope,
                                        float u, float y1,
                                        float& o0, float& o1) {
    float s  = fmaf(y1, INVH, TOFF);
    s = fminf(fmaxf(s, 0.0f), SMAX);
    float fl = floorf(s);
    float fr = s - fl;
    int   i  = (int)fl;
    float pv = lval[i];
    float ps = lslope[i];
    float r0 = fmaf(fr, ps, pv);                         // r(y1)
    float d1 = (fmaf(-kKK, y1, u) - (kOFFST + r0)) * kM; // yddoti[1]
    float t3 = (3.0f * 0.005f) * d1;                     // 3*DT*d1
    float lin = fmaf(6.0f, y1, t3);                      // 6y1+3DTd1
    o0 = -kC1 * lin;
    float rsum = fmaf(ps * INVH, t3, 6.0f * r0);         // 6r0 + r'*3DTd1
    float acc  = fmaf(-kKK, lin, fmaf(6.0f, u, -6.0f * kOFFST)) - rsum;
    o1 = kC1 * acc;
}

template <int NC>   // NC=64: fully unrolled; NC=0: runtime loop over nc
__global__ __launch_bounds__(256)
void rk_fused_kernel(const float* __restrict__ u_in,
                     const float* __restrict__ y1_in,
                     const float* __restrict__ centers,
                     const float* __restrict__ gammas,
                     const float* __restrict__ weights,
                     float* __restrict__ out, int B, int nc) {
    __shared__ float lval[NTAB];
    __shared__ float lslope[NTAB];
    const int tid = threadIdx.x;
    const long base = ((long)blockIdx.x * blockDim.x + tid) * EPT;
    const bool full = (base + EPT <= (long)B);

    // ---- issue ALL streaming loads early (land during table build) ----
    v4f uv[EPT / 4], yv[EPT / 4];
    if (full) {
        #pragma unroll
        for (int q = 0; q < EPT / 4; ++q) {
            uv[q] = *(const v4f*)(u_in  + base + 4 * q);
            yv[q] = *(const v4f*)(y1_in + base + 4 * q);
        }
    }

    // ---- per-block LUT build: thread tid -> entry tid ----
    {
        float x = XMIN + (float)tid * HSTEP;
        float v = 0.0f;
        if (NC > 0) {
            #pragma unroll
            for (int j = 0; j < NC; ++j) {
                float d = x - centers[j];
                v = fmaf(weights[j], __expf(-gammas[j] * d * d), v);
            }
        } else {
            for (int j = 0; j < nc; ++j) {
                float d = x - centers[j];
                v = fmaf(weights[j], __expf(-gammas[j] * d * d), v);
            }
        }
        lval[tid] = v;
    }
    __syncthreads();
    {
        float v0 = lval[tid];
        float sl = (tid < NTAB - 1) ? (lval[tid + 1] - v0) : 0.0f;
        lslope[tid] = sl;
    }
    __syncthreads();

    // ---- main streaming compute, EPT elements/thread ----
    if (full) {
        #pragma unroll
        for (int q = 0; q < EPT / 4; ++q) {
            float uu[4] = {uv[q].x, uv[q].y, uv[q].z, uv[q].w};
            float yy[4] = {yv[q].x, yv[q].y, yv[q].z, yv[q].w};
            float o0[4], o1[4];
            #pragma unroll
            for (int e = 0; e < 4; ++e)
                rk_core(lval, lslope, uu[e], yy[e], o0[e], o1[e]);
            v4f w0 = {o0[0], o0[1], o0[2], o0[3]};
            v4f w1 = {o1[0], o1[1], o1[2], o1[3]};
            *(v4f*)(out + base + 4 * q)     = w0;
            *(v4f*)(out + B + base + 4 * q) = w1;
        }
    } else {
        for (long e = base; e < (long)B && e < base + EPT; ++e) {
            float o0, o1;
            rk_core(lval, lslope, u_in[e], y1_in[e], o0, o1);
            out[e] = o0;
            out[B + e] = o1;
        }
    }
}

extern "C" void kernel_launch(void* const* d_in, const int* in_sizes, int n_in,
                              void* d_out, int out_size, void* d_ws, size_t ws_size,
                              hipStream_t stream) {
    const float* u       = (const float*)d_in[0];
    const float* states  = (const float*)d_in[1];
    const float* centers = (const float*)d_in[2];
    const float* gammas  = (const float*)d_in[3];
    const float* weights = (const float*)d_in[4];
    int B  = in_sizes[0];
    int nc = in_sizes[2];
    const float* y1 = states + B;                  // row 1 of states[2,B]
    float* out = (float*)d_out;

    int nthreads = (B + EPT - 1) / EPT;
    int nblocks  = (nthreads + 255) / 256;         // 256 thr x 16 elems -> 256 blocks at B=2^20
    if (nc == 64) {
        rk_fused_kernel<64><<<nblocks, 256, 0, stream>>>(u, y1, centers, gammas,
                                                         weights, out, B, nc);
    } else {
        rk_fused_kernel<0><<<nblocks, 256, 0, stream>>>(u, y1, centers, gammas,
                                                        weights, out, B, nc);
    }
}

// Round 8
// 10.263 us; speedup vs baseline: 1.3520x; 1.3520x over previous
//
#include <hip/hip_runtime.h>

// ---------------------------------------------------------------------------
// Fused RK4-ish integrator cell with RBF drift term. Output depends only on
// u and y1 = states[1]:
//   d1  = (u - KK*y1 - OFFST - r(y1)) * M          (KK = F_V + F_C)
//   lin = 6*y1 + 3*DT*d1
//   st0 = -(DT/6)*M * lin
//   st1 =  (DT/6)*M * (6u - KK*lin - 6*OFFST - rsum)
// rsum = r(y1) + 4 r(y1+.5*DT*d1) + r(y1+DT*d1) ~= 6*r0 + (sl/h)*3*DT*d1
// (first-order Taylor; verified absmax 2.4e-4 vs threshold 1.23e-3).
//
// Config ladder (measured): EPT=4/1024blk 15.3 | EPT=8/512blk 10.25 (BEST)
//   | EPT=8+NT-stores 11.25 (L2-resident working set; NT forces HBM)
//   | EPT=16/256blk 13.88 (1 wave/SIMD: no TLP, latency exposed).
// This round = R4 winner config + SoA LUT (two ds_read_b32, ~2-way random
// conflicts = free, vs 4-way on ds_read_b64 float2 AoS).
// ---------------------------------------------------------------------------

typedef float v4f __attribute__((ext_vector_type(4)));

#define NTAB   256
#define XMIN   (-8.0f)
#define HSTEP  0.0625f       // 16/256, exact pow2
#define INVH   16.0f
#define TOFF   128.0f        // -XMIN*INVH
#define SMAX   254.999f      // clamp so i+1 <= 255 (slope[255] unused)
#define EPT    8             // elements per thread (measured sweet spot)

__device__ __constant__ const float kM     = (float)(1.0 / 95.45);
__device__ __constant__ const float kOFFST = -3.2902f;
__device__ __constant__ const float kKK    = 214.9261f + 19.3607f;  // F_V+F_C
__device__ __constant__ const float kC1    = (0.005f / 6.0f) * (float)(1.0 / 95.45);

__device__ __forceinline__ void rk_core(const float* __restrict__ lval,
                                        const float* __restrict__ lslope,
                                        float u, float y1,
                                        float& o0, float& o1) {
    float s  = fmaf(y1, INVH, TOFF);
    s = fminf(fmaxf(s, 0.0f), SMAX);
    float fl = floorf(s);
    float fr = s - fl;
    int   i  = (int)fl;
    float pv = lval[i];
    float ps = lslope[i];
    float r0 = fmaf(fr, ps, pv);                         // r(y1)
    float d1 = (fmaf(-kKK, y1, u) - (kOFFST + r0)) * kM; // yddoti[1]
    float t3 = (3.0f * 0.005f) * d1;                     // 3*DT*d1
    float lin = fmaf(6.0f, y1, t3);                      // 6y1+3DTd1
    o0 = -kC1 * lin;
    float rsum = fmaf(ps * INVH, t3, 6.0f * r0);         // 6r0 + r'*3DTd1
    float acc  = fmaf(-kKK, lin, fmaf(6.0f, u, -6.0f * kOFFST)) - rsum;
    o1 = kC1 * acc;
}

template <int NC>   // NC=64: fully unrolled; NC=0: runtime loop over nc
__global__ __launch_bounds__(256)
void rk_fused_kernel(const float* __restrict__ u_in,
                     const float* __restrict__ y1_in,
                     const float* __restrict__ centers,
                     const float* __restrict__ gammas,
                     const float* __restrict__ weights,
                     float* __restrict__ out, int B, int nc) {
    __shared__ float lval[NTAB];
    __shared__ float lslope[NTAB];
    const int tid = threadIdx.x;
    const long base = ((long)blockIdx.x * blockDim.x + tid) * EPT;
    const bool full = (base + EPT <= (long)B);

    // ---- issue ALL streaming loads early (land during table build) ----
    v4f uv[EPT / 4], yv[EPT / 4];
    if (full) {
        #pragma unroll
        for (int q = 0; q < EPT / 4; ++q) {
            uv[q] = *(const v4f*)(u_in  + base + 4 * q);
            yv[q] = *(const v4f*)(y1_in + base + 4 * q);
        }
    }

    // ---- per-block LUT build: thread tid -> entry tid ----
    {
        float x = XMIN + (float)tid * HSTEP;
        float v = 0.0f;
        if (NC > 0) {
            #pragma unroll
            for (int j = 0; j < NC; ++j) {
                float d = x - centers[j];
                v = fmaf(weights[j], __expf(-gammas[j] * d * d), v);
            }
        } else {
            for (int j = 0; j < nc; ++j) {
                float d = x - centers[j];
                v = fmaf(weights[j], __expf(-gammas[j] * d * d), v);
            }
        }
        lval[tid] = v;
    }
    __syncthreads();
    {
        float v0 = lval[tid];
        float sl = (tid < NTAB - 1) ? (lval[tid + 1] - v0) : 0.0f;
        lslope[tid] = sl;
    }
    __syncthreads();

    // ---- main streaming compute, EPT elements/thread ----
    if (full) {
        #pragma unroll
        for (int q = 0; q < EPT / 4; ++q) {
            float uu[4] = {uv[q].x, uv[q].y, uv[q].z, uv[q].w};
            float yy[4] = {yv[q].x, yv[q].y, yv[q].z, yv[q].w};
            float o0[4], o1[4];
            #pragma unroll
            for (int e = 0; e < 4; ++e)
                rk_core(lval, lslope, uu[e], yy[e], o0[e], o1[e]);
            v4f w0 = {o0[0], o0[1], o0[2], o0[3]};
            v4f w1 = {o1[0], o1[1], o1[2], o1[3]};
            *(v4f*)(out + base + 4 * q)     = w0;
            *(v4f*)(out + B + base + 4 * q) = w1;
        }
    } else {
        for (long e = base; e < (long)B && e < base + EPT; ++e) {
            float o0, o1;
            rk_core(lval, lslope, u_in[e], y1_in[e], o0, o1);
            out[e] = o0;
            out[B + e] = o1;
        }
    }
}

extern "C" void kernel_launch(void* const* d_in, const int* in_sizes, int n_in,
                              void* d_out, int out_size, void* d_ws, size_t ws_size,
                              hipStream_t stream) {
    const float* u       = (const float*)d_in[0];
    const float* states  = (const float*)d_in[1];
    const float* centers = (const float*)d_in[2];
    const float* gammas  = (const float*)d_in[3];
    const float* weights = (const float*)d_in[4];
    int B  = in_sizes[0];
    int nc = in_sizes[2];
    const float* y1 = states + B;                  // row 1 of states[2,B]
    float* out = (float*)d_out;

    int nthreads = (B + EPT - 1) / EPT;
    int nblocks  = (nthreads + 255) / 256;         // 512 blocks at B=2^20
    if (nc == 64) {
        rk_fused_kernel<64><<<nblocks, 256, 0, stream>>>(u, y1, centers, gammas,
                                                         weights, out, B, nc);
    } else {
        rk_fused_kernel<0><<<nblocks, 256, 0, stream>>>(u, y1, centers, gammas,
                                                        weights, out, B, nc);
    }
}